// Round 10
// baseline (196.571 us; speedup 1.0000x reference)
//
#include <hip/hip_runtime.h>

#define BK_SHIFT 7
#define BK_NODES 128          // nodes per bucket
#define CAP      5120         // slot stride per bucket (raw max ~3450 + pad8 <= ~4350)
#define MAXNBK   800          // max buckets (N=100000 -> 782)
#define EPW      8192         // edges per workgroup in k_bin (16 per thread @512T)

// ---- non-temporal load/store helpers (stream data, keep L2 for gathers) ----
typedef int   v4i __attribute__((ext_vector_type(4)));
typedef float v4f __attribute__((ext_vector_type(4)));

static __device__ __forceinline__ int4 ntload4i(const int* p) {
    v4i v = __builtin_nontemporal_load((const v4i*)p);
    return make_int4(v.x, v.y, v.z, v.w);
}
static __device__ __forceinline__ float4 ntload4f(const float* p) {
    v4f v = __builtin_nontemporal_load((const v4f*)p);
    return make_float4(v.x, v.y, v.z, v.w);
}
static __device__ __forceinline__ void ntstore4f(float* p, float4 v) {
    v4f w = {v.x, v.y, v.z, v.w};
    __builtin_nontemporal_store(w, (v4f*)p);
}

// ---------------- phase A: bin edges by target bucket ----------------
// single LDS histogram; after reservation hist[b] holds the global cursor,
// so pass-2 LDS atomicAdd returns the final slot directly. 512 threads,
// EPW=8192 -> 306 blocks. Lane-stride-16B int4 loads stay coalesced;
// col values cached in registers between the two passes.
// packed word: (local_t << 17) | src   (src <= N < 2^17, local_t < 128)

__global__ __launch_bounds__(512) void k_bin(const int* __restrict__ row,
                                             const int* __restrict__ col,
                                             int* __restrict__ bcursor,
                                             int* __restrict__ bucketbuf,
                                             int E, int nbk) {
    __shared__ int hist[MAXNBK];
    int tid = threadIdx.x;
    for (int i = tid; i < nbk; i += 512) hist[i] = 0;
    __syncthreads();
    int e0 = blockIdx.x * EPW;
    int eend = min(e0 + EPW, E);
    bool full = (eend - e0) == EPW;
    int4 c0, c1, c2, c3;
    if (full) {
        int base = e0 + tid * 4;
        c0 = *(const int4*)(col + base);
        c1 = *(const int4*)(col + base + 2048);
        c2 = *(const int4*)(col + base + 4096);
        c3 = *(const int4*)(col + base + 6144);
        atomicAdd(&hist[c0.x >> BK_SHIFT], 1); atomicAdd(&hist[c0.y >> BK_SHIFT], 1);
        atomicAdd(&hist[c0.z >> BK_SHIFT], 1); atomicAdd(&hist[c0.w >> BK_SHIFT], 1);
        atomicAdd(&hist[c1.x >> BK_SHIFT], 1); atomicAdd(&hist[c1.y >> BK_SHIFT], 1);
        atomicAdd(&hist[c1.z >> BK_SHIFT], 1); atomicAdd(&hist[c1.w >> BK_SHIFT], 1);
        atomicAdd(&hist[c2.x >> BK_SHIFT], 1); atomicAdd(&hist[c2.y >> BK_SHIFT], 1);
        atomicAdd(&hist[c2.z >> BK_SHIFT], 1); atomicAdd(&hist[c2.w >> BK_SHIFT], 1);
        atomicAdd(&hist[c3.x >> BK_SHIFT], 1); atomicAdd(&hist[c3.y >> BK_SHIFT], 1);
        atomicAdd(&hist[c3.z >> BK_SHIFT], 1); atomicAdd(&hist[c3.w >> BK_SHIFT], 1);
    } else {
        for (int e = e0 + tid; e < eend; e += 512)
            atomicAdd(&hist[col[e] >> BK_SHIFT], 1);
    }
    __syncthreads();
    // reserve global ranges; hist becomes the global cursor
    for (int i = tid; i < nbk; i += 512) {
        int h = hist[i];
        hist[i] = h ? atomicAdd(&bcursor[i], h) : 0;
    }
    __syncthreads();
    // pass 2: place (row loaded coalesced, col from registers)
    if (full) {
        int base = e0 + tid * 4;
        int4 r0 = *(const int4*)(row + base);
        int4 r1 = *(const int4*)(row + base + 2048);
        int4 r2 = *(const int4*)(row + base + 4096);
        int4 r3 = *(const int4*)(row + base + 6144);
        int b, p;
        #define PLACE(T, S) \
            b = (T) >> BK_SHIFT; p = atomicAdd(&hist[b], 1); \
            if (p < CAP) bucketbuf[b * CAP + p] = (((T) & (BK_NODES - 1)) << 17) | (S);
        PLACE(c0.x, r0.x) PLACE(c0.y, r0.y) PLACE(c0.z, r0.z) PLACE(c0.w, r0.w)
        PLACE(c1.x, r1.x) PLACE(c1.y, r1.y) PLACE(c1.z, r1.z) PLACE(c1.w, r1.w)
        PLACE(c2.x, r2.x) PLACE(c2.y, r2.y) PLACE(c2.z, r2.z) PLACE(c2.w, r2.w)
        PLACE(c3.x, r3.x) PLACE(c3.y, r3.y) PLACE(c3.z, r3.z) PLACE(c3.w, r3.w)
        #undef PLACE
    } else {
        for (int e = e0 + tid; e < eend; e += 512) {
            int t = col[e], s = row[e];
            int b = t >> BK_SHIFT;
            int p = atomicAdd(&hist[b], 1);
            if (p < CAP) bucketbuf[b * CAP + p] = ((t & (BK_NODES - 1)) << 17) | s;
        }
    }
}

// ---------------- phase B: per-bucket LDS counting sort -> padded CSR ----------------
// Bucket edges cached in LDS on first read (single global pass). Per-node
// segments padded to %8 with dummy src=N (row N zeroed -> 0 contribution).
// Sorted list written back in place into bucketbuf (fixed stride CAP).
// Also emits dis, and x8 = x * dis (PRE-SCALED features for layer 1).

__global__ __launch_bounds__(256) void k_build(int* __restrict__ bucketbuf,
                                               const int* __restrict__ bcursor,
                                               int2* __restrict__ span,
                                               float* __restrict__ dis,
                                               const float* __restrict__ x,
                                               float* __restrict__ x8,
                                               float* __restrict__ P0,
                                               float* __restrict__ P1,
                                               int N, int nbk) {
    __shared__ int deg_s[BK_NODES];
    __shared__ int scan_s[BK_NODES];
    __shared__ int off_s[BK_NODES + 1];
    __shared__ int cur_s[BK_NODES];
    __shared__ float dis_s[BK_NODES];
    __shared__ int ledge[CAP];
    __shared__ int lout[CAP];
    int bkt = blockIdx.x;
    int node0 = bkt << BK_SHIFT;
    int nn = min(BK_NODES, N - node0);
    int cnt = min(bcursor[bkt], CAP);
    int gbase = bkt * CAP;
    int tid = threadIdx.x;
    if (tid < BK_NODES) deg_s[tid] = 0;
    __syncthreads();
    int* buf = bucketbuf + (size_t)gbase;
    // single global read: cache edges in LDS + histogram
    for (int i = tid; i < cnt; i += 256) {
        int w = buf[i];
        ledge[i] = w;
        atomicAdd(&deg_s[w >> 17], 1);
    }
    __syncthreads();
    // parallel inclusive scan of padded degrees (entries >= nn are 0)
    int pd = (tid < BK_NODES) ? ((deg_s[tid] + 7) & ~7) : 0;
    if (tid < BK_NODES) scan_s[tid] = pd;
    __syncthreads();
    #pragma unroll
    for (int o = 1; o < BK_NODES; o <<= 1) {
        int v = (tid < BK_NODES && tid >= o) ? scan_s[tid - o] : 0;
        __syncthreads();
        if (tid < BK_NODES) scan_s[tid] += v;
        __syncthreads();
    }
    if (tid < BK_NODES) off_s[tid] = scan_s[tid] - pd;   // exclusive
    if (tid == 0) off_s[BK_NODES] = scan_s[BK_NODES - 1];
    __syncthreads();
    int total = scan_s[BK_NODES - 1];
    if (tid < nn) {
        cur_s[tid] = off_s[tid];
        span[node0 + tid] = make_int2(gbase + off_s[tid], gbase + off_s[tid + 1]);
        float d = rsqrtf((float)(deg_s[tid] + 1));   // +1 self loop
        dis_s[tid] = d;
        dis[node0 + tid] = d;
    }
    __syncthreads();
    for (int i = tid; i < total; i += 256) lout[i] = N;       // dummy fill
    for (int i = tid; i < nn * 8; i += 256) {
        int ln = i >> 3, c2 = i & 7;
        int n = node0 + ln;
        x8[(size_t)n * 8 + c2] = (c2 < 6) ? x[(size_t)n * 6 + c2] * dis_s[ln] : 0.f;
    }
    if (bkt == 0) {
        if (tid < 32) { P0[(size_t)N * 32 + tid] = 0.f; P1[(size_t)N * 32 + tid] = 0.f; }
        if (tid < 8)  x8[(size_t)N * 8 + tid] = 0.f;
        if (tid == 32) dis[N] = 0.f;
    }
    __syncthreads();
    for (int i = tid; i < cnt; i += 256) {
        int w = ledge[i];
        int r = atomicAdd(&cur_s[w >> 17], 1);
        lout[r] = w & 0x1FFFF;
    }
    __syncthreads();
    for (int i = tid; i < total; i += 256)
        buf[i] = lout[i];
}

// ---------------- layer 1 fused: ya = (sum xd[s] + xd[t])*dn; out = tanh(ya@W1+b1)*dn ----
// Inputs pre-scaled by dis -> inner loop is pure float4 adds.
// 2 lanes per node (float4 each); 8-unrolled gather (x8 is L2-resident); LDS epilogue.

__global__ __launch_bounds__(256) void k_agg8f(const float* __restrict__ x8,
                                               const int2* __restrict__ span,
                                               const int* __restrict__ csr,
                                               const float* __restrict__ dis,
                                               const float* __restrict__ W1,
                                               const float* __restrict__ b1,
                                               float* __restrict__ out, int N) {
    __shared__ float xa_s[128][9];
    __shared__ float W_s[6 * 32];
    __shared__ float b_s[32];
    int tid = threadIdx.x;
    for (int i = tid; i < 192; i += 256) W_s[i] = W1[i];
    if (tid < 32) b_s[tid] = b1[tid];
    int ln = tid >> 1, h = tid & 1;
    int t = blockIdx.x * 128 + ln;
    float4 r = {0, 0, 0, 0};
    float dn = 0.f;
    if (t < N) {
        dn = dis[t];
        const float4* x4 = (const float4*)x8;
        float4 self = x4[(size_t)t * 2 + h];
        int2 be = span[t];
        int k = be.x, end = be.y;
        float4 a0 = self, a1 = {0, 0, 0, 0};
        if (k < end) {
            int4 sa = ntload4i(csr + k);
            int4 sb = ntload4i(csr + k + 4);
            for (;;) {
                int kn = k + 8;
                int4 na, nb;
                bool more = kn < end;
                if (more) { na = ntload4i(csr + kn); nb = ntload4i(csr + kn + 4); }
                float4 v0 = x4[(size_t)sa.x * 2 + h];
                float4 v1 = x4[(size_t)sa.y * 2 + h];
                float4 v2 = x4[(size_t)sa.z * 2 + h];
                float4 v3 = x4[(size_t)sa.w * 2 + h];
                float4 v4 = x4[(size_t)sb.x * 2 + h];
                float4 v5 = x4[(size_t)sb.y * 2 + h];
                float4 v6 = x4[(size_t)sb.z * 2 + h];
                float4 v7 = x4[(size_t)sb.w * 2 + h];
                a0.x += v0.x + v1.x + v2.x + v3.x;
                a0.y += v0.y + v1.y + v2.y + v3.y;
                a0.z += v0.z + v1.z + v2.z + v3.z;
                a0.w += v0.w + v1.w + v2.w + v3.w;
                a1.x += v4.x + v5.x + v6.x + v7.x;
                a1.y += v4.y + v5.y + v6.y + v7.y;
                a1.z += v4.z + v5.z + v6.z + v7.z;
                a1.w += v4.w + v5.w + v6.w + v7.w;
                if (!more) break;
                sa = na; sb = nb; k = kn;
            }
        }
        r.x = (a0.x + a1.x) * dn;
        r.y = (a0.y + a1.y) * dn;
        r.z = (a0.z + a1.z) * dn;
        r.w = (a0.w + a1.w) * dn;
    }
    xa_s[ln][h * 4 + 0] = r.x;
    xa_s[ln][h * 4 + 1] = r.y;
    xa_s[ln][h * 4 + 2] = r.z;
    xa_s[ln][h * 4 + 3] = r.w;
    __syncthreads();
    if (t < N) {
        float a[6];
        #pragma unroll
        for (int k = 0; k < 6; ++k) a[k] = xa_s[ln][k];
        #pragma unroll 1
        for (int cc = 0; cc < 4; ++cc) {
            int c0 = h * 16 + cc * 4;
            float4 o = *(const float4*)&b_s[c0];
            #pragma unroll
            for (int k = 0; k < 6; ++k) {
                float4 w = *(const float4*)&W_s[k * 32 + c0];
                o.x += a[k] * w.x; o.y += a[k] * w.y;
                o.z += a[k] * w.z; o.w += a[k] * w.w;
            }
            o.x = tanhf(o.x) * dn; o.y = tanhf(o.y) * dn;
            o.z = tanhf(o.z) * dn; o.w = tanhf(o.w) * dn;
            ntstore4f(out + (size_t)t * 32 + c0, o);
        }
    }
}

// ---------------- layers 2/3 fused: A = (sum hd[s] + hd[t])*dn; out = tanh(A@W+b) ----
// Inputs pre-scaled by dis -> pure-add inner loop. CSR stream NT-loaded, output
// NT-stored (no L2 reuse) to keep L2 capacity for the feature gathers.

template <bool PRESCALE>
__global__ __launch_bounds__(256) void k_aggmm(const float* __restrict__ hfeat,
                                               const int2* __restrict__ span,
                                               const int* __restrict__ csr,
                                               const float* __restrict__ dis,
                                               const float* __restrict__ W,
                                               const float* __restrict__ b,
                                               float* __restrict__ out, int N) {
    __shared__ float agg_s[32][36];
    __shared__ float W_s[32 * 32];
    int tid = threadIdx.x;
    for (int i = tid; i < 1024; i += 256) W_s[i] = W[i];
    int ln = tid >> 3, q = tid & 7;
    int t = blockIdx.x * 32 + ln;
    float4 r = {0, 0, 0, 0};
    float dn = 0.f;
    if (t < N) {
        dn = dis[t];
        const float4* h4 = (const float4*)hfeat;
        float4 self = h4[(size_t)t * 8 + q];
        int2 be = span[t];
        int k = be.x, end = be.y;
        float4 a0 = self, a1 = {0, 0, 0, 0};
        if (k < end) {
            int4 sa = ntload4i(csr + k);
            int4 sb = ntload4i(csr + k + 4);
            for (;;) {
                int kn = k + 8;
                int4 na, nb;
                bool more = kn < end;
                if (more) { na = ntload4i(csr + kn); nb = ntload4i(csr + kn + 4); }
                float4 v0 = h4[(size_t)sa.x * 8 + q];
                float4 v1 = h4[(size_t)sa.y * 8 + q];
                float4 v2 = h4[(size_t)sa.z * 8 + q];
                float4 v3 = h4[(size_t)sa.w * 8 + q];
                float4 v4 = h4[(size_t)sb.x * 8 + q];
                float4 v5 = h4[(size_t)sb.y * 8 + q];
                float4 v6 = h4[(size_t)sb.z * 8 + q];
                float4 v7 = h4[(size_t)sb.w * 8 + q];
                a0.x += v0.x + v1.x + v2.x + v3.x;
                a0.y += v0.y + v1.y + v2.y + v3.y;
                a0.z += v0.z + v1.z + v2.z + v3.z;
                a0.w += v0.w + v1.w + v2.w + v3.w;
                a1.x += v4.x + v5.x + v6.x + v7.x;
                a1.y += v4.y + v5.y + v6.y + v7.y;
                a1.z += v4.z + v5.z + v6.z + v7.z;
                a1.w += v4.w + v5.w + v6.w + v7.w;
                if (!more) break;
                sa = na; sb = nb; k = kn;
            }
        }
        r.x = (a0.x + a1.x) * dn;
        r.y = (a0.y + a1.y) * dn;
        r.z = (a0.z + a1.z) * dn;
        r.w = (a0.w + a1.w) * dn;
    }
    agg_s[ln][q * 4 + 0] = r.x;
    agg_s[ln][q * 4 + 1] = r.y;
    agg_s[ln][q * 4 + 2] = r.z;
    agg_s[ln][q * 4 + 3] = r.w;
    __syncthreads();
    if (t < N) {
        const float4* W4 = (const float4*)W_s;
        const float4* b4 = (const float4*)b;
        float4 o = b4[q];
        #pragma unroll 4
        for (int k = 0; k < 32; ++k) {
            float a = agg_s[ln][k];
            float4 w = W4[k * 8 + q];
            o.x += a * w.x; o.y += a * w.y; o.z += a * w.z; o.w += a * w.w;
        }
        if (PRESCALE) {
            o.x = tanhf(o.x) * dn; o.y = tanhf(o.y) * dn;
            o.z = tanhf(o.z) * dn; o.w = tanhf(o.w) * dn;
        } else {
            o.x = tanhf(o.x); o.y = tanhf(o.y);
            o.z = tanhf(o.z); o.w = tanhf(o.w);
        }
        ntstore4f(out + (size_t)t * 32 + q * 4, o);
    }
}

// ---------------- fused pooling + classifier ----------------
// 32 lanes per graph: 8 channel-chunk lanes x 4 node-ways (ILP), shfl reduce.

__global__ __launch_bounds__(256) void k_poolfinal(const float* __restrict__ h,
                                                   const int* __restrict__ batch,
                                                   const float* __restrict__ Wc,
                                                   const float* __restrict__ bc,
                                                   float* __restrict__ out,
                                                   int N, int G) {
    int idx = blockIdx.x * blockDim.x + threadIdx.x;
    int g = idx >> 5;
    int lane = idx & 31;
    int q = lane & 7;        // float4 channel chunk 0..7
    int w = lane >> 3;       // node way 0..3
    if (g >= G) return;
    int lo = 0, hi = N;
    while (lo < hi) { int m = (lo + hi) >> 1; if (batch[m] < g) lo = m + 1; else hi = m; }
    int s = lo;
    hi = N;
    while (lo < hi) { int m = (lo + hi) >> 1; if (batch[m] < g + 1) lo = m + 1; else hi = m; }
    int e = lo;
    float4 acc = {0, 0, 0, 0};
    for (int n = s + w; n < e; n += 4) {
        float4 v = ntload4f(h + (size_t)n * 32 + q * 4);
        acc.x += v.x; acc.y += v.y; acc.z += v.z; acc.w += v.w;
    }
    // reduce the 4 node-ways (lanes differing in bits 3..4)
    #pragma unroll
    for (int m = 8; m <= 16; m <<= 1) {
        acc.x += __shfl_xor(acc.x, m);
        acc.y += __shfl_xor(acc.y, m);
        acc.z += __shfl_xor(acc.z, m);
        acc.w += __shfl_xor(acc.w, m);
    }
    float inv = 1.f / (float)max(e - s, 1);
    acc.x *= inv; acc.y *= inv; acc.z *= inv; acc.w *= inv;
    float p[6];
    #pragma unroll
    for (int v = 0; v < 6; ++v) {
        p[v] = acc.x * Wc[(4 * q + 0) * 6 + v] + acc.y * Wc[(4 * q + 1) * 6 + v]
             + acc.z * Wc[(4 * q + 2) * 6 + v] + acc.w * Wc[(4 * q + 3) * 6 + v];
    }
    #pragma unroll
    for (int m = 4; m >= 1; m >>= 1) {
        #pragma unroll
        for (int v = 0; v < 6; ++v) p[v] += __shfl_xor(p[v], m);
    }
    if (lane < 6) out[(size_t)g * 6 + lane] = p[lane] + bc[lane];
}

// ---------------- launch ----------------

extern "C" void kernel_launch(void* const* d_in, const int* in_sizes, int n_in,
                              void* d_out, int out_size, void* d_ws, size_t ws_size,
                              hipStream_t stream) {
    const float* x  = (const float*)d_in[0];
    const int*   ei = (const int*)d_in[1];
    const int*   batch = (const int*)d_in[2];
    const float* W1 = (const float*)d_in[3];
    const float* b1 = (const float*)d_in[4];
    const float* W2 = (const float*)d_in[5];
    const float* b2 = (const float*)d_in[6];
    const float* W3 = (const float*)d_in[7];
    const float* b3 = (const float*)d_in[8];
    const float* Wc = (const float*)d_in[9];
    const float* bc = (const float*)d_in[10];
    float* out = (float*)d_out;

    const int N = in_sizes[0] / 6;
    const int E = in_sizes[1] / 2;
    const int G = out_size / 6;
    const int* row = ei;        // edge_index[0] = source
    const int* col = ei + E;    // edge_index[1] = target
    const int nbk = (N + BK_NODES - 1) >> BK_SHIFT;   // 782

    char* ws = (char*)d_ws;
    size_t off = 0;
    auto alloc = [&](size_t bytes) -> void* {
        void* p = ws + off;
        off = (off + bytes + 255) & ~(size_t)255;
        return p;
    };
    int*   bcursor  = (int*)  alloc((size_t)nbk * 4);
    int*   bucketbuf= (int*)  alloc((size_t)nbk * CAP * 4);    // 16 MB (becomes CSR)
    int2*  span     = (int2*) alloc((size_t)N * 8);
    float* dis      = (float*)alloc((size_t)(N + 1) * 4);
    float* x8       = (float*)alloc((size_t)(N + 1) * 8 * 4);
    float* P0       = (float*)alloc((size_t)(N + 1) * 32 * 4);
    float* P1       = (float*)alloc((size_t)(N + 1) * 32 * 4);

    const int T = 256;
    hipMemsetAsync(bcursor, 0, (size_t)nbk * 4, stream);

    int nwgA = (E + EPW - 1) / EPW;
    k_bin  <<<nwgA, 512, 0, stream>>>(row, col, bcursor, bucketbuf, E, nbk);
    k_build<<<nbk, T, 0, stream>>>(bucketbuf, bcursor, span, dis, x, x8, P0, P1, N, nbk);

    // layer 1: gather-add pre-scaled raw features + fused 6->32 matmul+bias+tanh (*dis)
    k_agg8f<<<(N + 127) / 128, T, 0, stream>>>(x8, span, bucketbuf, dis, W1, b1, P0, N);
    // layers 2,3: gather-add pre-scaled h + fused 32x32 matmul+bias+tanh
    k_aggmm<true> <<<(N + 31) / 32, T, 0, stream>>>(P0, span, bucketbuf, dis, W2, b2, P1, N);
    k_aggmm<false><<<(N + 31) / 32, T, 0, stream>>>(P1, span, bucketbuf, dis, W3, b3, P0, N);

    k_poolfinal<<<(G * 32 + T - 1) / T, T, 0, stream>>>(P0, batch, Wc, bc, out, N, G);
}

// Round 11
// 175.580 us; speedup vs baseline: 1.1196x; 1.1196x over previous
//
#include <hip/hip_runtime.h>

#define BK_SHIFT 7
#define BK_NODES 128          // nodes per bucket
#define CAP      5120         // slot stride per bucket (raw max ~3450 + pad8 <= ~4350)
#define MAXNBK   800          // max buckets (N=100000 -> 782)
#define EPW      8192         // edges per workgroup in k_bin (16 per thread @512T)

// ---------------- phase A: bin edges by target bucket ----------------
// single LDS histogram; after reservation hist[b] holds the global cursor,
// so pass-2 LDS atomicAdd returns the final slot directly. 512 threads,
// EPW=8192 -> 306 blocks. Lane-stride-16B int4 loads stay coalesced;
// col values cached in registers between the two passes.
// packed word: (local_t << 17) | src   (src <= N < 2^17, local_t < 128)

__global__ __launch_bounds__(512) void k_bin(const int* __restrict__ row,
                                             const int* __restrict__ col,
                                             int* __restrict__ bcursor,
                                             int* __restrict__ bucketbuf,
                                             int E, int nbk) {
    __shared__ int hist[MAXNBK];
    int tid = threadIdx.x;
    for (int i = tid; i < nbk; i += 512) hist[i] = 0;
    __syncthreads();
    int e0 = blockIdx.x * EPW;
    int eend = min(e0 + EPW, E);
    bool full = (eend - e0) == EPW;
    int4 c0, c1, c2, c3;
    if (full) {
        int base = e0 + tid * 4;
        c0 = *(const int4*)(col + base);
        c1 = *(const int4*)(col + base + 2048);
        c2 = *(const int4*)(col + base + 4096);
        c3 = *(const int4*)(col + base + 6144);
        atomicAdd(&hist[c0.x >> BK_SHIFT], 1); atomicAdd(&hist[c0.y >> BK_SHIFT], 1);
        atomicAdd(&hist[c0.z >> BK_SHIFT], 1); atomicAdd(&hist[c0.w >> BK_SHIFT], 1);
        atomicAdd(&hist[c1.x >> BK_SHIFT], 1); atomicAdd(&hist[c1.y >> BK_SHIFT], 1);
        atomicAdd(&hist[c1.z >> BK_SHIFT], 1); atomicAdd(&hist[c1.w >> BK_SHIFT], 1);
        atomicAdd(&hist[c2.x >> BK_SHIFT], 1); atomicAdd(&hist[c2.y >> BK_SHIFT], 1);
        atomicAdd(&hist[c2.z >> BK_SHIFT], 1); atomicAdd(&hist[c2.w >> BK_SHIFT], 1);
        atomicAdd(&hist[c3.x >> BK_SHIFT], 1); atomicAdd(&hist[c3.y >> BK_SHIFT], 1);
        atomicAdd(&hist[c3.z >> BK_SHIFT], 1); atomicAdd(&hist[c3.w >> BK_SHIFT], 1);
    } else {
        for (int e = e0 + tid; e < eend; e += 512)
            atomicAdd(&hist[col[e] >> BK_SHIFT], 1);
    }
    __syncthreads();
    // reserve global ranges; hist becomes the global cursor
    for (int i = tid; i < nbk; i += 512) {
        int h = hist[i];
        hist[i] = h ? atomicAdd(&bcursor[i], h) : 0;
    }
    __syncthreads();
    // pass 2: place (row loaded coalesced, col from registers)
    if (full) {
        int base = e0 + tid * 4;
        int4 r0 = *(const int4*)(row + base);
        int4 r1 = *(const int4*)(row + base + 2048);
        int4 r2 = *(const int4*)(row + base + 4096);
        int4 r3 = *(const int4*)(row + base + 6144);
        int b, p;
        #define PLACE(T, S) \
            b = (T) >> BK_SHIFT; p = atomicAdd(&hist[b], 1); \
            if (p < CAP) bucketbuf[b * CAP + p] = (((T) & (BK_NODES - 1)) << 17) | (S);
        PLACE(c0.x, r0.x) PLACE(c0.y, r0.y) PLACE(c0.z, r0.z) PLACE(c0.w, r0.w)
        PLACE(c1.x, r1.x) PLACE(c1.y, r1.y) PLACE(c1.z, r1.z) PLACE(c1.w, r1.w)
        PLACE(c2.x, r2.x) PLACE(c2.y, r2.y) PLACE(c2.z, r2.z) PLACE(c2.w, r2.w)
        PLACE(c3.x, r3.x) PLACE(c3.y, r3.y) PLACE(c3.z, r3.z) PLACE(c3.w, r3.w)
        #undef PLACE
    } else {
        for (int e = e0 + tid; e < eend; e += 512) {
            int t = col[e], s = row[e];
            int b = t >> BK_SHIFT;
            int p = atomicAdd(&hist[b], 1);
            if (p < CAP) bucketbuf[b * CAP + p] = ((t & (BK_NODES - 1)) << 17) | s;
        }
    }
}

// ---------------- phase B: per-bucket LDS counting sort -> padded CSR ----------------
// Bucket edges cached in LDS on first read (single global pass). Per-node
// segments padded to %8 with dummy src=N (row N zeroed -> 0 contribution).
// Sorted list written back in place into bucketbuf (fixed stride CAP).
// Also emits dis, and x8 = x * dis (PRE-SCALED features for layer 1).

__global__ __launch_bounds__(256) void k_build(int* __restrict__ bucketbuf,
                                               const int* __restrict__ bcursor,
                                               int2* __restrict__ span,
                                               float* __restrict__ dis,
                                               const float* __restrict__ x,
                                               float* __restrict__ x8,
                                               float* __restrict__ P0,
                                               float* __restrict__ P1,
                                               int N, int nbk) {
    __shared__ int deg_s[BK_NODES];
    __shared__ int scan_s[BK_NODES];
    __shared__ int off_s[BK_NODES + 1];
    __shared__ int cur_s[BK_NODES];
    __shared__ float dis_s[BK_NODES];
    __shared__ int ledge[CAP];
    __shared__ int lout[CAP];
    int bkt = blockIdx.x;
    int node0 = bkt << BK_SHIFT;
    int nn = min(BK_NODES, N - node0);
    int cnt = min(bcursor[bkt], CAP);
    int gbase = bkt * CAP;
    int tid = threadIdx.x;
    if (tid < BK_NODES) deg_s[tid] = 0;
    __syncthreads();
    int* buf = bucketbuf + (size_t)gbase;
    // single global read: cache edges in LDS + histogram
    for (int i = tid; i < cnt; i += 256) {
        int w = buf[i];
        ledge[i] = w;
        atomicAdd(&deg_s[w >> 17], 1);
    }
    __syncthreads();
    // parallel inclusive scan of padded degrees (entries >= nn are 0)
    int pd = (tid < BK_NODES) ? ((deg_s[tid] + 7) & ~7) : 0;
    if (tid < BK_NODES) scan_s[tid] = pd;
    __syncthreads();
    #pragma unroll
    for (int o = 1; o < BK_NODES; o <<= 1) {
        int v = (tid < BK_NODES && tid >= o) ? scan_s[tid - o] : 0;
        __syncthreads();
        if (tid < BK_NODES) scan_s[tid] += v;
        __syncthreads();
    }
    if (tid < BK_NODES) off_s[tid] = scan_s[tid] - pd;   // exclusive
    if (tid == 0) off_s[BK_NODES] = scan_s[BK_NODES - 1];
    __syncthreads();
    int total = scan_s[BK_NODES - 1];
    if (tid < nn) {
        cur_s[tid] = off_s[tid];
        span[node0 + tid] = make_int2(gbase + off_s[tid], gbase + off_s[tid + 1]);
        float d = rsqrtf((float)(deg_s[tid] + 1));   // +1 self loop
        dis_s[tid] = d;
        dis[node0 + tid] = d;
    }
    __syncthreads();
    for (int i = tid; i < total; i += 256) lout[i] = N;       // dummy fill
    for (int i = tid; i < nn * 8; i += 256) {
        int ln = i >> 3, c2 = i & 7;
        int n = node0 + ln;
        x8[(size_t)n * 8 + c2] = (c2 < 6) ? x[(size_t)n * 6 + c2] * dis_s[ln] : 0.f;
    }
    if (bkt == 0) {
        if (tid < 32) { P0[(size_t)N * 32 + tid] = 0.f; P1[(size_t)N * 32 + tid] = 0.f; }
        if (tid < 8)  x8[(size_t)N * 8 + tid] = 0.f;
        if (tid == 32) dis[N] = 0.f;
    }
    __syncthreads();
    for (int i = tid; i < cnt; i += 256) {
        int w = ledge[i];
        int r = atomicAdd(&cur_s[w >> 17], 1);
        lout[r] = w & 0x1FFFF;
    }
    __syncthreads();
    for (int i = tid; i < total; i += 256)
        buf[i] = lout[i];
}

// ---------------- layer 1 fused: ya = (sum xd[s] + xd[t])*dn; out = tanh(ya@W1+b1)*dn ----
// Inputs pre-scaled by dis -> inner loop is pure float4 adds.
// 2 lanes per node (float4 each); 8-unrolled gather (x8 is L2-resident); LDS epilogue.

__global__ __launch_bounds__(256) void k_agg8f(const float* __restrict__ x8,
                                               const int2* __restrict__ span,
                                               const int* __restrict__ csr,
                                               const float* __restrict__ dis,
                                               const float* __restrict__ W1,
                                               const float* __restrict__ b1,
                                               float* __restrict__ out, int N) {
    __shared__ float xa_s[128][9];
    __shared__ float W_s[6 * 32];
    __shared__ float b_s[32];
    int tid = threadIdx.x;
    for (int i = tid; i < 192; i += 256) W_s[i] = W1[i];
    if (tid < 32) b_s[tid] = b1[tid];
    int ln = tid >> 1, h = tid & 1;
    int t = blockIdx.x * 128 + ln;
    float4 r = {0, 0, 0, 0};
    float dn = 0.f;
    if (t < N) {
        dn = dis[t];
        const float4* x4 = (const float4*)x8;
        float4 self = x4[(size_t)t * 2 + h];
        int2 be = span[t];
        int k = be.x, end = be.y;
        float4 a0 = self, a1 = {0, 0, 0, 0};
        if (k < end) {
            int4 sa = *(const int4*)(csr + k);
            int4 sb = *(const int4*)(csr + k + 4);
            for (;;) {
                int kn = k + 8;
                int4 na, nb;
                bool more = kn < end;
                if (more) { na = *(const int4*)(csr + kn); nb = *(const int4*)(csr + kn + 4); }
                float4 v0 = x4[(size_t)sa.x * 2 + h];
                float4 v1 = x4[(size_t)sa.y * 2 + h];
                float4 v2 = x4[(size_t)sa.z * 2 + h];
                float4 v3 = x4[(size_t)sa.w * 2 + h];
                float4 v4 = x4[(size_t)sb.x * 2 + h];
                float4 v5 = x4[(size_t)sb.y * 2 + h];
                float4 v6 = x4[(size_t)sb.z * 2 + h];
                float4 v7 = x4[(size_t)sb.w * 2 + h];
                a0.x += v0.x + v1.x + v2.x + v3.x;
                a0.y += v0.y + v1.y + v2.y + v3.y;
                a0.z += v0.z + v1.z + v2.z + v3.z;
                a0.w += v0.w + v1.w + v2.w + v3.w;
                a1.x += v4.x + v5.x + v6.x + v7.x;
                a1.y += v4.y + v5.y + v6.y + v7.y;
                a1.z += v4.z + v5.z + v6.z + v7.z;
                a1.w += v4.w + v5.w + v6.w + v7.w;
                if (!more) break;
                sa = na; sb = nb; k = kn;
            }
        }
        r.x = (a0.x + a1.x) * dn;
        r.y = (a0.y + a1.y) * dn;
        r.z = (a0.z + a1.z) * dn;
        r.w = (a0.w + a1.w) * dn;
    }
    xa_s[ln][h * 4 + 0] = r.x;
    xa_s[ln][h * 4 + 1] = r.y;
    xa_s[ln][h * 4 + 2] = r.z;
    xa_s[ln][h * 4 + 3] = r.w;
    __syncthreads();
    if (t < N) {
        float a[6];
        #pragma unroll
        for (int k = 0; k < 6; ++k) a[k] = xa_s[ln][k];
        #pragma unroll 1
        for (int cc = 0; cc < 4; ++cc) {
            int c0 = h * 16 + cc * 4;
            float4 o = *(const float4*)&b_s[c0];
            #pragma unroll
            for (int k = 0; k < 6; ++k) {
                float4 w = *(const float4*)&W_s[k * 32 + c0];
                o.x += a[k] * w.x; o.y += a[k] * w.y;
                o.z += a[k] * w.z; o.w += a[k] * w.w;
            }
            o.x = tanhf(o.x) * dn; o.y = tanhf(o.y) * dn;
            o.z = tanhf(o.z) * dn; o.w = tanhf(o.w) * dn;
            ((float4*)out)[(size_t)t * 8 + (c0 >> 2)] = o;
        }
    }
}

// ---------------- layers 2/3 fused: A = (sum hd[s] + hd[t])*dn; out = tanh(A@W+b) ----
// Inputs pre-scaled by dis -> pure-add inner loop. Plain loads/stores: outputs
// feed the next layer's gathers, so keeping them in L2 matters (NT regressed, r10).

template <bool PRESCALE>
__global__ __launch_bounds__(256) void k_aggmm(const float* __restrict__ hfeat,
                                               const int2* __restrict__ span,
                                               const int* __restrict__ csr,
                                               const float* __restrict__ dis,
                                               const float* __restrict__ W,
                                               const float* __restrict__ b,
                                               float* __restrict__ out, int N) {
    __shared__ float agg_s[32][36];
    __shared__ float W_s[32 * 32];
    int tid = threadIdx.x;
    for (int i = tid; i < 1024; i += 256) W_s[i] = W[i];
    int ln = tid >> 3, q = tid & 7;
    int t = blockIdx.x * 32 + ln;
    float4 r = {0, 0, 0, 0};
    float dn = 0.f;
    if (t < N) {
        dn = dis[t];
        const float4* h4 = (const float4*)hfeat;
        float4 self = h4[(size_t)t * 8 + q];
        int2 be = span[t];
        int k = be.x, end = be.y;
        float4 a0 = self, a1 = {0, 0, 0, 0};
        if (k < end) {
            int4 sa = *(const int4*)(csr + k);
            int4 sb = *(const int4*)(csr + k + 4);
            for (;;) {
                int kn = k + 8;
                int4 na, nb;
                bool more = kn < end;
                if (more) { na = *(const int4*)(csr + kn); nb = *(const int4*)(csr + kn + 4); }
                float4 v0 = h4[(size_t)sa.x * 8 + q];
                float4 v1 = h4[(size_t)sa.y * 8 + q];
                float4 v2 = h4[(size_t)sa.z * 8 + q];
                float4 v3 = h4[(size_t)sa.w * 8 + q];
                float4 v4 = h4[(size_t)sb.x * 8 + q];
                float4 v5 = h4[(size_t)sb.y * 8 + q];
                float4 v6 = h4[(size_t)sb.z * 8 + q];
                float4 v7 = h4[(size_t)sb.w * 8 + q];
                a0.x += v0.x + v1.x + v2.x + v3.x;
                a0.y += v0.y + v1.y + v2.y + v3.y;
                a0.z += v0.z + v1.z + v2.z + v3.z;
                a0.w += v0.w + v1.w + v2.w + v3.w;
                a1.x += v4.x + v5.x + v6.x + v7.x;
                a1.y += v4.y + v5.y + v6.y + v7.y;
                a1.z += v4.z + v5.z + v6.z + v7.z;
                a1.w += v4.w + v5.w + v6.w + v7.w;
                if (!more) break;
                sa = na; sb = nb; k = kn;
            }
        }
        r.x = (a0.x + a1.x) * dn;
        r.y = (a0.y + a1.y) * dn;
        r.z = (a0.z + a1.z) * dn;
        r.w = (a0.w + a1.w) * dn;
    }
    agg_s[ln][q * 4 + 0] = r.x;
    agg_s[ln][q * 4 + 1] = r.y;
    agg_s[ln][q * 4 + 2] = r.z;
    agg_s[ln][q * 4 + 3] = r.w;
    __syncthreads();
    if (t < N) {
        const float4* W4 = (const float4*)W_s;
        const float4* b4 = (const float4*)b;
        float4 o = b4[q];
        #pragma unroll 4
        for (int k = 0; k < 32; ++k) {
            float a = agg_s[ln][k];
            float4 w = W4[k * 8 + q];
            o.x += a * w.x; o.y += a * w.y; o.z += a * w.z; o.w += a * w.w;
        }
        if (PRESCALE) {
            o.x = tanhf(o.x) * dn; o.y = tanhf(o.y) * dn;
            o.z = tanhf(o.z) * dn; o.w = tanhf(o.w) * dn;
        } else {
            o.x = tanhf(o.x); o.y = tanhf(o.y);
            o.z = tanhf(o.z); o.w = tanhf(o.w);
        }
        ((float4*)out)[(size_t)t * 8 + q] = o;
    }
}

// ---------------- fused pooling + classifier ----------------
// 32 lanes per graph: 8 channel-chunk lanes x 4 node-ways (ILP), shfl reduce.

__global__ __launch_bounds__(256) void k_poolfinal(const float* __restrict__ h,
                                                   const int* __restrict__ batch,
                                                   const float* __restrict__ Wc,
                                                   const float* __restrict__ bc,
                                                   float* __restrict__ out,
                                                   int N, int G) {
    int idx = blockIdx.x * blockDim.x + threadIdx.x;
    int g = idx >> 5;
    int lane = idx & 31;
    int q = lane & 7;        // float4 channel chunk 0..7
    int w = lane >> 3;       // node way 0..3
    if (g >= G) return;
    int lo = 0, hi = N;
    while (lo < hi) { int m = (lo + hi) >> 1; if (batch[m] < g) lo = m + 1; else hi = m; }
    int s = lo;
    hi = N;
    while (lo < hi) { int m = (lo + hi) >> 1; if (batch[m] < g + 1) lo = m + 1; else hi = m; }
    int e = lo;
    const float4* h4 = (const float4*)h;
    float4 acc = {0, 0, 0, 0};
    for (int n = s + w; n < e; n += 4) {
        float4 v = h4[(size_t)n * 8 + q];
        acc.x += v.x; acc.y += v.y; acc.z += v.z; acc.w += v.w;
    }
    // reduce the 4 node-ways (lanes differing in bits 3..4)
    #pragma unroll
    for (int m = 8; m <= 16; m <<= 1) {
        acc.x += __shfl_xor(acc.x, m);
        acc.y += __shfl_xor(acc.y, m);
        acc.z += __shfl_xor(acc.z, m);
        acc.w += __shfl_xor(acc.w, m);
    }
    float inv = 1.f / (float)max(e - s, 1);
    acc.x *= inv; acc.y *= inv; acc.z *= inv; acc.w *= inv;
    float p[6];
    #pragma unroll
    for (int v = 0; v < 6; ++v) {
        p[v] = acc.x * Wc[(4 * q + 0) * 6 + v] + acc.y * Wc[(4 * q + 1) * 6 + v]
             + acc.z * Wc[(4 * q + 2) * 6 + v] + acc.w * Wc[(4 * q + 3) * 6 + v];
    }
    #pragma unroll
    for (int m = 4; m >= 1; m >>= 1) {
        #pragma unroll
        for (int v = 0; v < 6; ++v) p[v] += __shfl_xor(p[v], m);
    }
    if (lane < 6) out[(size_t)g * 6 + lane] = p[lane] + bc[lane];
}

// ---------------- launch ----------------

extern "C" void kernel_launch(void* const* d_in, const int* in_sizes, int n_in,
                              void* d_out, int out_size, void* d_ws, size_t ws_size,
                              hipStream_t stream) {
    const float* x  = (const float*)d_in[0];
    const int*   ei = (const int*)d_in[1];
    const int*   batch = (const int*)d_in[2];
    const float* W1 = (const float*)d_in[3];
    const float* b1 = (const float*)d_in[4];
    const float* W2 = (const float*)d_in[5];
    const float* b2 = (const float*)d_in[6];
    const float* W3 = (const float*)d_in[7];
    const float* b3 = (const float*)d_in[8];
    const float* Wc = (const float*)d_in[9];
    const float* bc = (const float*)d_in[10];
    float* out = (float*)d_out;

    const int N = in_sizes[0] / 6;
    const int E = in_sizes[1] / 2;
    const int G = out_size / 6;
    const int* row = ei;        // edge_index[0] = source
    const int* col = ei + E;    // edge_index[1] = target
    const int nbk = (N + BK_NODES - 1) >> BK_SHIFT;   // 782

    char* ws = (char*)d_ws;
    size_t off = 0;
    auto alloc = [&](size_t bytes) -> void* {
        void* p = ws + off;
        off = (off + bytes + 255) & ~(size_t)255;
        return p;
    };
    int*   bcursor  = (int*)  alloc((size_t)nbk * 4);
    int*   bucketbuf= (int*)  alloc((size_t)nbk * CAP * 4);    // 16 MB (becomes CSR)
    int2*  span     = (int2*) alloc((size_t)N * 8);
    float* dis      = (float*)alloc((size_t)(N + 1) * 4);
    float* x8       = (float*)alloc((size_t)(N + 1) * 8 * 4);
    float* P0       = (float*)alloc((size_t)(N + 1) * 32 * 4);
    float* P1       = (float*)alloc((size_t)(N + 1) * 32 * 4);

    const int T = 256;
    hipMemsetAsync(bcursor, 0, (size_t)nbk * 4, stream);

    int nwgA = (E + EPW - 1) / EPW;
    k_bin  <<<nwgA, 512, 0, stream>>>(row, col, bcursor, bucketbuf, E, nbk);
    k_build<<<nbk, T, 0, stream>>>(bucketbuf, bcursor, span, dis, x, x8, P0, P1, N, nbk);

    // layer 1: gather-add pre-scaled raw features + fused 6->32 matmul+bias+tanh (*dis)
    k_agg8f<<<(N + 127) / 128, T, 0, stream>>>(x8, span, bucketbuf, dis, W1, b1, P0, N);
    // layers 2,3: gather-add pre-scaled h + fused 32x32 matmul+bias+tanh
    k_aggmm<true> <<<(N + 31) / 32, T, 0, stream>>>(P0, span, bucketbuf, dis, W2, b2, P1, N);
    k_aggmm<false><<<(N + 31) / 32, T, 0, stream>>>(P1, span, bucketbuf, dis, W3, b3, P0, N);

    k_poolfinal<<<(G * 32 + T - 1) / T, T, 0, stream>>>(P0, batch, Wc, bc, out, N, G);
}

// Round 12
// 152.886 us; speedup vs baseline: 1.2857x; 1.1484x over previous
//
#include <hip/hip_runtime.h>

#define BK_SHIFT 7
#define BK_NODES 128          // nodes per bucket
#define CAP      5120         // slot stride per bucket (raw max ~3450 + pad8 <= ~4350)
#define MAXNBK   800          // max buckets (N=100000 -> 782)
#define EPW      8192         // edges per workgroup in k_bin (16 per thread @512T)

typedef __attribute__((ext_vector_type(4))) _Float16 half4;

// ---------------- phase A: bin edges by target bucket ----------------
// single LDS histogram; after reservation hist[b] holds the global cursor,
// so pass-2 LDS atomicAdd returns the final slot directly. 512 threads,
// EPW=8192 -> 306 blocks. Lane-stride-16B int4 loads stay coalesced;
// col values cached in registers between the two passes.
// packed word: (local_t << 17) | src   (src <= N < 2^17, local_t < 128)

__global__ __launch_bounds__(512) void k_bin(const int* __restrict__ row,
                                             const int* __restrict__ col,
                                             int* __restrict__ bcursor,
                                             int* __restrict__ bucketbuf,
                                             int E, int nbk) {
    __shared__ int hist[MAXNBK];
    int tid = threadIdx.x;
    for (int i = tid; i < nbk; i += 512) hist[i] = 0;
    __syncthreads();
    int e0 = blockIdx.x * EPW;
    int eend = min(e0 + EPW, E);
    bool full = (eend - e0) == EPW;
    int4 c0, c1, c2, c3;
    if (full) {
        int base = e0 + tid * 4;
        c0 = *(const int4*)(col + base);
        c1 = *(const int4*)(col + base + 2048);
        c2 = *(const int4*)(col + base + 4096);
        c3 = *(const int4*)(col + base + 6144);
        atomicAdd(&hist[c0.x >> BK_SHIFT], 1); atomicAdd(&hist[c0.y >> BK_SHIFT], 1);
        atomicAdd(&hist[c0.z >> BK_SHIFT], 1); atomicAdd(&hist[c0.w >> BK_SHIFT], 1);
        atomicAdd(&hist[c1.x >> BK_SHIFT], 1); atomicAdd(&hist[c1.y >> BK_SHIFT], 1);
        atomicAdd(&hist[c1.z >> BK_SHIFT], 1); atomicAdd(&hist[c1.w >> BK_SHIFT], 1);
        atomicAdd(&hist[c2.x >> BK_SHIFT], 1); atomicAdd(&hist[c2.y >> BK_SHIFT], 1);
        atomicAdd(&hist[c2.z >> BK_SHIFT], 1); atomicAdd(&hist[c2.w >> BK_SHIFT], 1);
        atomicAdd(&hist[c3.x >> BK_SHIFT], 1); atomicAdd(&hist[c3.y >> BK_SHIFT], 1);
        atomicAdd(&hist[c3.z >> BK_SHIFT], 1); atomicAdd(&hist[c3.w >> BK_SHIFT], 1);
    } else {
        for (int e = e0 + tid; e < eend; e += 512)
            atomicAdd(&hist[col[e] >> BK_SHIFT], 1);
    }
    __syncthreads();
    // reserve global ranges; hist becomes the global cursor
    for (int i = tid; i < nbk; i += 512) {
        int h = hist[i];
        hist[i] = h ? atomicAdd(&bcursor[i], h) : 0;
    }
    __syncthreads();
    // pass 2: place (row loaded coalesced, col from registers)
    if (full) {
        int base = e0 + tid * 4;
        int4 r0 = *(const int4*)(row + base);
        int4 r1 = *(const int4*)(row + base + 2048);
        int4 r2 = *(const int4*)(row + base + 4096);
        int4 r3 = *(const int4*)(row + base + 6144);
        int b, p;
        #define PLACE(T, S) \
            b = (T) >> BK_SHIFT; p = atomicAdd(&hist[b], 1); \
            if (p < CAP) bucketbuf[b * CAP + p] = (((T) & (BK_NODES - 1)) << 17) | (S);
        PLACE(c0.x, r0.x) PLACE(c0.y, r0.y) PLACE(c0.z, r0.z) PLACE(c0.w, r0.w)
        PLACE(c1.x, r1.x) PLACE(c1.y, r1.y) PLACE(c1.z, r1.z) PLACE(c1.w, r1.w)
        PLACE(c2.x, r2.x) PLACE(c2.y, r2.y) PLACE(c2.z, r2.z) PLACE(c2.w, r2.w)
        PLACE(c3.x, r3.x) PLACE(c3.y, r3.y) PLACE(c3.z, r3.z) PLACE(c3.w, r3.w)
        #undef PLACE
    } else {
        for (int e = e0 + tid; e < eend; e += 512) {
            int t = col[e], s = row[e];
            int b = t >> BK_SHIFT;
            int p = atomicAdd(&hist[b], 1);
            if (p < CAP) bucketbuf[b * CAP + p] = ((t & (BK_NODES - 1)) << 17) | s;
        }
    }
}

// ---------------- phase B: per-bucket LDS counting sort -> padded CSR ----------------
// Bucket edges cached in LDS on first read (single global pass). Per-node
// segments padded to %8 with dummy src=N (row N zeroed -> 0 contribution).
// Sorted list written back in place into bucketbuf (fixed stride CAP).
// Also emits dis, x8 = x * dis (fp32), and zeros row N of the fp16 buffers.

__global__ __launch_bounds__(256) void k_build(int* __restrict__ bucketbuf,
                                               const int* __restrict__ bcursor,
                                               int2* __restrict__ span,
                                               float* __restrict__ dis,
                                               const float* __restrict__ x,
                                               float* __restrict__ x8,
                                               _Float16* __restrict__ PH0,
                                               _Float16* __restrict__ PH1,
                                               int N, int nbk) {
    __shared__ int deg_s[BK_NODES];
    __shared__ int scan_s[BK_NODES];
    __shared__ int off_s[BK_NODES + 1];
    __shared__ int cur_s[BK_NODES];
    __shared__ float dis_s[BK_NODES];
    __shared__ int ledge[CAP];
    __shared__ int lout[CAP];
    int bkt = blockIdx.x;
    int node0 = bkt << BK_SHIFT;
    int nn = min(BK_NODES, N - node0);
    int cnt = min(bcursor[bkt], CAP);
    int gbase = bkt * CAP;
    int tid = threadIdx.x;
    if (tid < BK_NODES) deg_s[tid] = 0;
    __syncthreads();
    int* buf = bucketbuf + (size_t)gbase;
    // single global read: cache edges in LDS + histogram
    for (int i = tid; i < cnt; i += 256) {
        int w = buf[i];
        ledge[i] = w;
        atomicAdd(&deg_s[w >> 17], 1);
    }
    __syncthreads();
    // parallel inclusive scan of padded degrees (entries >= nn are 0)
    int pd = (tid < BK_NODES) ? ((deg_s[tid] + 7) & ~7) : 0;
    if (tid < BK_NODES) scan_s[tid] = pd;
    __syncthreads();
    #pragma unroll
    for (int o = 1; o < BK_NODES; o <<= 1) {
        int v = (tid < BK_NODES && tid >= o) ? scan_s[tid - o] : 0;
        __syncthreads();
        if (tid < BK_NODES) scan_s[tid] += v;
        __syncthreads();
    }
    if (tid < BK_NODES) off_s[tid] = scan_s[tid] - pd;   // exclusive
    if (tid == 0) off_s[BK_NODES] = scan_s[BK_NODES - 1];
    __syncthreads();
    int total = scan_s[BK_NODES - 1];
    if (tid < nn) {
        cur_s[tid] = off_s[tid];
        span[node0 + tid] = make_int2(gbase + off_s[tid], gbase + off_s[tid + 1]);
        float d = rsqrtf((float)(deg_s[tid] + 1));   // +1 self loop
        dis_s[tid] = d;
        dis[node0 + tid] = d;
    }
    __syncthreads();
    for (int i = tid; i < total; i += 256) lout[i] = N;       // dummy fill
    for (int i = tid; i < nn * 8; i += 256) {
        int ln = i >> 3, c2 = i & 7;
        int n = node0 + ln;
        x8[(size_t)n * 8 + c2] = (c2 < 6) ? x[(size_t)n * 6 + c2] * dis_s[ln] : 0.f;
    }
    if (bkt == 0) {
        // zero dummy row N: 32 halves = 16 ints per buffer
        if (tid < 16) { ((int*)PH0)[(size_t)N * 16 + tid] = 0; ((int*)PH1)[(size_t)N * 16 + tid] = 0; }
        if (tid >= 16 && tid < 24) x8[(size_t)N * 8 + (tid - 16)] = 0.f;
        if (tid == 32) dis[N] = 0.f;
    }
    __syncthreads();
    for (int i = tid; i < cnt; i += 256) {
        int w = ledge[i];
        int r = atomicAdd(&cur_s[w >> 17], 1);
        lout[r] = w & 0x1FFFF;
    }
    __syncthreads();
    for (int i = tid; i < total; i += 256)
        buf[i] = lout[i];
}

// ---------------- layer 1 fused: ya = (sum xd[s] + xd[t])*dn; out = fp16(tanh(ya@W1+b1)*dn) ----
// Inputs pre-scaled by dis (fp32, L2-resident); output quantized to fp16 for
// layer 2's half-width gathers. 2 lanes per node; LDS epilogue.

__global__ __launch_bounds__(256) void k_agg8f(const float* __restrict__ x8,
                                               const int2* __restrict__ span,
                                               const int* __restrict__ csr,
                                               const float* __restrict__ dis,
                                               const float* __restrict__ W1,
                                               const float* __restrict__ b1,
                                               _Float16* __restrict__ out, int N) {
    __shared__ float xa_s[128][9];
    __shared__ float W_s[6 * 32];
    __shared__ float b_s[32];
    int tid = threadIdx.x;
    for (int i = tid; i < 192; i += 256) W_s[i] = W1[i];
    if (tid < 32) b_s[tid] = b1[tid];
    int ln = tid >> 1, h = tid & 1;
    int t = blockIdx.x * 128 + ln;
    float4 r = {0, 0, 0, 0};
    float dn = 0.f;
    if (t < N) {
        dn = dis[t];
        const float4* x4 = (const float4*)x8;
        float4 self = x4[(size_t)t * 2 + h];
        int2 be = span[t];
        int k = be.x, end = be.y;
        float4 a0 = self, a1 = {0, 0, 0, 0};
        if (k < end) {
            int4 sa = *(const int4*)(csr + k);
            int4 sb = *(const int4*)(csr + k + 4);
            for (;;) {
                int kn = k + 8;
                int4 na, nb;
                bool more = kn < end;
                if (more) { na = *(const int4*)(csr + kn); nb = *(const int4*)(csr + kn + 4); }
                float4 v0 = x4[(size_t)sa.x * 2 + h];
                float4 v1 = x4[(size_t)sa.y * 2 + h];
                float4 v2 = x4[(size_t)sa.z * 2 + h];
                float4 v3 = x4[(size_t)sa.w * 2 + h];
                float4 v4 = x4[(size_t)sb.x * 2 + h];
                float4 v5 = x4[(size_t)sb.y * 2 + h];
                float4 v6 = x4[(size_t)sb.z * 2 + h];
                float4 v7 = x4[(size_t)sb.w * 2 + h];
                a0.x += v0.x + v1.x + v2.x + v3.x;
                a0.y += v0.y + v1.y + v2.y + v3.y;
                a0.z += v0.z + v1.z + v2.z + v3.z;
                a0.w += v0.w + v1.w + v2.w + v3.w;
                a1.x += v4.x + v5.x + v6.x + v7.x;
                a1.y += v4.y + v5.y + v6.y + v7.y;
                a1.z += v4.z + v5.z + v6.z + v7.z;
                a1.w += v4.w + v5.w + v6.w + v7.w;
                if (!more) break;
                sa = na; sb = nb; k = kn;
            }
        }
        r.x = (a0.x + a1.x) * dn;
        r.y = (a0.y + a1.y) * dn;
        r.z = (a0.z + a1.z) * dn;
        r.w = (a0.w + a1.w) * dn;
    }
    xa_s[ln][h * 4 + 0] = r.x;
    xa_s[ln][h * 4 + 1] = r.y;
    xa_s[ln][h * 4 + 2] = r.z;
    xa_s[ln][h * 4 + 3] = r.w;
    __syncthreads();
    if (t < N) {
        float a[6];
        #pragma unroll
        for (int k = 0; k < 6; ++k) a[k] = xa_s[ln][k];
        #pragma unroll 1
        for (int cc = 0; cc < 4; ++cc) {
            int c0 = h * 16 + cc * 4;
            float4 o = *(const float4*)&b_s[c0];
            #pragma unroll
            for (int k = 0; k < 6; ++k) {
                float4 w = *(const float4*)&W_s[k * 32 + c0];
                o.x += a[k] * w.x; o.y += a[k] * w.y;
                o.z += a[k] * w.z; o.w += a[k] * w.w;
            }
            half4 oh;
            oh.x = (_Float16)(tanhf(o.x) * dn);
            oh.y = (_Float16)(tanhf(o.y) * dn);
            oh.z = (_Float16)(tanhf(o.z) * dn);
            oh.w = (_Float16)(tanhf(o.w) * dn);
            *(half4*)(out + (size_t)t * 32 + c0) = oh;
        }
    }
}

// ---------------- layers 2/3 fused: A = (sum hd[s] + hd[t])*dn; out = tanh(A@W+b) ----
// fp16 feature rows (64 B = one line per edge) halve the gather traffic vs fp32;
// accumulation in fp32. PRESCALE=true writes fp16 (next layer's gathers);
// final layer writes fp32 for pooling precision.

template <bool PRESCALE>
__global__ __launch_bounds__(256) void k_aggmm(const _Float16* __restrict__ hfeat,
                                               const int2* __restrict__ span,
                                               const int* __restrict__ csr,
                                               const float* __restrict__ dis,
                                               const float* __restrict__ W,
                                               const float* __restrict__ b,
                                               _Float16* __restrict__ outh,
                                               float* __restrict__ outf, int N) {
    __shared__ float agg_s[32][36];
    __shared__ float W_s[32 * 32];
    int tid = threadIdx.x;
    for (int i = tid; i < 1024; i += 256) W_s[i] = W[i];
    int ln = tid >> 3, q = tid & 7;
    int t = blockIdx.x * 32 + ln;
    float4 r = {0, 0, 0, 0};
    float dn = 0.f;
    if (t < N) {
        dn = dis[t];
        const half4* h4 = (const half4*)hfeat;
        half4 sf = h4[(size_t)t * 8 + q];
        int2 be = span[t];
        int k = be.x, end = be.y;
        float4 a0, a1 = {0, 0, 0, 0};
        a0.x = (float)sf.x; a0.y = (float)sf.y; a0.z = (float)sf.z; a0.w = (float)sf.w;
        if (k < end) {
            int4 sa = *(const int4*)(csr + k);
            int4 sb = *(const int4*)(csr + k + 4);
            for (;;) {
                int kn = k + 8;
                int4 na, nb;
                bool more = kn < end;
                if (more) { na = *(const int4*)(csr + kn); nb = *(const int4*)(csr + kn + 4); }
                half4 v0 = h4[(size_t)sa.x * 8 + q];
                half4 v1 = h4[(size_t)sa.y * 8 + q];
                half4 v2 = h4[(size_t)sa.z * 8 + q];
                half4 v3 = h4[(size_t)sa.w * 8 + q];
                half4 v4 = h4[(size_t)sb.x * 8 + q];
                half4 v5 = h4[(size_t)sb.y * 8 + q];
                half4 v6 = h4[(size_t)sb.z * 8 + q];
                half4 v7 = h4[(size_t)sb.w * 8 + q];
                a0.x += (float)v0.x + (float)v1.x + (float)v2.x + (float)v3.x;
                a0.y += (float)v0.y + (float)v1.y + (float)v2.y + (float)v3.y;
                a0.z += (float)v0.z + (float)v1.z + (float)v2.z + (float)v3.z;
                a0.w += (float)v0.w + (float)v1.w + (float)v2.w + (float)v3.w;
                a1.x += (float)v4.x + (float)v5.x + (float)v6.x + (float)v7.x;
                a1.y += (float)v4.y + (float)v5.y + (float)v6.y + (float)v7.y;
                a1.z += (float)v4.z + (float)v5.z + (float)v6.z + (float)v7.z;
                a1.w += (float)v4.w + (float)v5.w + (float)v6.w + (float)v7.w;
                if (!more) break;
                sa = na; sb = nb; k = kn;
            }
        }
        r.x = (a0.x + a1.x) * dn;
        r.y = (a0.y + a1.y) * dn;
        r.z = (a0.z + a1.z) * dn;
        r.w = (a0.w + a1.w) * dn;
    }
    agg_s[ln][q * 4 + 0] = r.x;
    agg_s[ln][q * 4 + 1] = r.y;
    agg_s[ln][q * 4 + 2] = r.z;
    agg_s[ln][q * 4 + 3] = r.w;
    __syncthreads();
    if (t < N) {
        const float4* W4 = (const float4*)W_s;
        const float4* b4 = (const float4*)b;
        float4 o = b4[q];
        #pragma unroll 4
        for (int k = 0; k < 32; ++k) {
            float a = agg_s[ln][k];
            float4 w = W4[k * 8 + q];
            o.x += a * w.x; o.y += a * w.y; o.z += a * w.z; o.w += a * w.w;
        }
        if (PRESCALE) {
            half4 oh;
            oh.x = (_Float16)(tanhf(o.x) * dn);
            oh.y = (_Float16)(tanhf(o.y) * dn);
            oh.z = (_Float16)(tanhf(o.z) * dn);
            oh.w = (_Float16)(tanhf(o.w) * dn);
            ((half4*)outh)[(size_t)t * 8 + q] = oh;
        } else {
            o.x = tanhf(o.x); o.y = tanhf(o.y);
            o.z = tanhf(o.z); o.w = tanhf(o.w);
            ((float4*)outf)[(size_t)t * 8 + q] = o;
        }
    }
}

// ---------------- fused pooling + classifier ----------------
// 32 lanes per graph: 8 channel-chunk lanes x 4 node-ways (ILP), shfl reduce.

__global__ __launch_bounds__(256) void k_poolfinal(const float* __restrict__ h,
                                                   const int* __restrict__ batch,
                                                   const float* __restrict__ Wc,
                                                   const float* __restrict__ bc,
                                                   float* __restrict__ out,
                                                   int N, int G) {
    int idx = blockIdx.x * blockDim.x + threadIdx.x;
    int g = idx >> 5;
    int lane = idx & 31;
    int q = lane & 7;        // float4 channel chunk 0..7
    int w = lane >> 3;       // node way 0..3
    if (g >= G) return;
    int lo = 0, hi = N;
    while (lo < hi) { int m = (lo + hi) >> 1; if (batch[m] < g) lo = m + 1; else hi = m; }
    int s = lo;
    hi = N;
    while (lo < hi) { int m = (lo + hi) >> 1; if (batch[m] < g + 1) lo = m + 1; else hi = m; }
    int e = lo;
    const float4* h4 = (const float4*)h;
    float4 acc = {0, 0, 0, 0};
    for (int n = s + w; n < e; n += 4) {
        float4 v = h4[(size_t)n * 8 + q];
        acc.x += v.x; acc.y += v.y; acc.z += v.z; acc.w += v.w;
    }
    // reduce the 4 node-ways (lanes differing in bits 3..4)
    #pragma unroll
    for (int m = 8; m <= 16; m <<= 1) {
        acc.x += __shfl_xor(acc.x, m);
        acc.y += __shfl_xor(acc.y, m);
        acc.z += __shfl_xor(acc.z, m);
        acc.w += __shfl_xor(acc.w, m);
    }
    float inv = 1.f / (float)max(e - s, 1);
    acc.x *= inv; acc.y *= inv; acc.z *= inv; acc.w *= inv;
    float p[6];
    #pragma unroll
    for (int v = 0; v < 6; ++v) {
        p[v] = acc.x * Wc[(4 * q + 0) * 6 + v] + acc.y * Wc[(4 * q + 1) * 6 + v]
             + acc.z * Wc[(4 * q + 2) * 6 + v] + acc.w * Wc[(4 * q + 3) * 6 + v];
    }
    #pragma unroll
    for (int m = 4; m >= 1; m >>= 1) {
        #pragma unroll
        for (int v = 0; v < 6; ++v) p[v] += __shfl_xor(p[v], m);
    }
    if (lane < 6) out[(size_t)g * 6 + lane] = p[lane] + bc[lane];
}

// ---------------- launch ----------------

extern "C" void kernel_launch(void* const* d_in, const int* in_sizes, int n_in,
                              void* d_out, int out_size, void* d_ws, size_t ws_size,
                              hipStream_t stream) {
    const float* x  = (const float*)d_in[0];
    const int*   ei = (const int*)d_in[1];
    const int*   batch = (const int*)d_in[2];
    const float* W1 = (const float*)d_in[3];
    const float* b1 = (const float*)d_in[4];
    const float* W2 = (const float*)d_in[5];
    const float* b2 = (const float*)d_in[6];
    const float* W3 = (const float*)d_in[7];
    const float* b3 = (const float*)d_in[8];
    const float* Wc = (const float*)d_in[9];
    const float* bc = (const float*)d_in[10];
    float* out = (float*)d_out;

    const int N = in_sizes[0] / 6;
    const int E = in_sizes[1] / 2;
    const int G = out_size / 6;
    const int* row = ei;        // edge_index[0] = source
    const int* col = ei + E;    // edge_index[1] = target
    const int nbk = (N + BK_NODES - 1) >> BK_SHIFT;   // 782

    char* ws = (char*)d_ws;
    size_t off = 0;
    auto alloc = [&](size_t bytes) -> void* {
        void* p = ws + off;
        off = (off + bytes + 255) & ~(size_t)255;
        return p;
    };
    int*      bcursor  = (int*)     alloc((size_t)nbk * 4);
    int*      bucketbuf= (int*)     alloc((size_t)nbk * CAP * 4);   // 16 MB (becomes CSR)
    int2*     span     = (int2*)    alloc((size_t)N * 8);
    float*    dis      = (float*)   alloc((size_t)(N + 1) * 4);
    float*    x8       = (float*)   alloc((size_t)(N + 1) * 8 * 4);
    _Float16* PH0      = (_Float16*)alloc((size_t)(N + 1) * 32 * 2); // 6.4 MB
    _Float16* PH1      = (_Float16*)alloc((size_t)(N + 1) * 32 * 2); // 6.4 MB
    float*    P32      = (float*)   alloc((size_t)N * 32 * 4);       // 12.8 MB

    const int T = 256;
    hipMemsetAsync(bcursor, 0, (size_t)nbk * 4, stream);

    int nwgA = (E + EPW - 1) / EPW;
    k_bin  <<<nwgA, 512, 0, stream>>>(row, col, bcursor, bucketbuf, E, nbk);
    k_build<<<nbk, T, 0, stream>>>(bucketbuf, bcursor, span, dis, x, x8, PH0, PH1, N, nbk);

    // layer 1: gather-add pre-scaled raw features (fp32) -> fp16 output
    k_agg8f<<<(N + 127) / 128, T, 0, stream>>>(x8, span, bucketbuf, dis, W1, b1, PH0, N);
    // layers 2,3: fp16 gather-add + fused 32x32 matmul+bias+tanh
    k_aggmm<true> <<<(N + 31) / 32, T, 0, stream>>>(PH0, span, bucketbuf, dis, W2, b2, PH1, nullptr, N);
    k_aggmm<false><<<(N + 31) / 32, T, 0, stream>>>(PH1, span, bucketbuf, dis, W3, b3, nullptr, P32, N);

    k_poolfinal<<<(G * 32 + T - 1) / T, T, 0, stream>>>(P32, batch, Wc, bc, out, N, G);
}